// Round 11
// baseline (77.001 us; speedup 1.0000x reference)
//
#include <hip/hip_runtime.h>
#include <math.h>

// Problem constants (reference: B=2048, CI=32, CO=32, A=16, ITER_NUM=5)
constexpr int CI = 32;
constexpr int CO = 32;
constexpr float INV_N   = 1.0f / 65536.0f;
constexpr float INV_NM1 = 1.0f / 65535.0f;

constexpr int NCHUNK = 64;                 // stats chunks per capsule
constexpr int PART_STRIDE = 272;           // 16 rows * 17 (16 cols + 1 sum)

// d_ws float layout (no zero-init required):
//   WS_PART: [CI][NCHUNK][272] per-block partials, canonical row*17+col
//   WS_WG:   [CI][16][16]  folded W*gamma
//   WS_C0:   [CI][16]      folded bias: beta - (mean @ W)*gamma
constexpr int WS_PART = 0;
constexpr int WS_WG   = CI * NCHUNK * PART_STRIDE;   // 557056
constexpr int WS_C0   = WS_WG + CI * 256;

using f32x4  = __attribute__((ext_vector_type(4))) float;
using bf16x8 = __attribute__((ext_vector_type(8))) short;

// fp32 -> bf16 (round-to-nearest-even), branch-free.
__device__ __forceinline__ unsigned short f2bf(float f) {
    const unsigned int u = __float_as_uint(f);
    return (unsigned short)((u + 0x7FFFu + ((u >> 16) & 1u)) >> 16);
}

// ---------------------------------------------------------------------------
// Kernel 1 (MFMA): per-capsule raw sums S[a] and Gram P[a][b] = sum x_a x_b.
// Grid: 32 ci * 64 chunks = 2048 blocks of 256 threads (8 blocks/CU, 8
// waves/SIMD -- R10 ran 4/SIMD and stalled at 3.6 TB/s; Little's law needs
// ~9.2 KB/SIMD in flight, this gives 8 waves x 2KB x depth-2).
// One mfma_f32_16x16x32_bf16 consumes 32 vectors (one batch's 32 co-slots).
// Gram trick: A and B fragments are IDENTICAL per-lane (row/col = lane&15,
// k = (lane>>4)*8+reg), so one 8-dword load feeds both; internal k-perm
// cancels in the k-sum; P symmetric. S accumulated in exact fp32.
// ---------------------------------------------------------------------------
__global__ __launch_bounds__(256) void k_stats(const float* __restrict__ x,
                                               float* __restrict__ ws) {
    const int ci    = blockIdx.x & 31;
    const int chunk = blockIdx.x >> 5;          // 0..63
    const int tid   = threadIdx.x;
    const int lane  = tid & 63;
    const int wv    = tid >> 6;
    const int m     = lane & 15;                // row/col index this lane owns
    const int g     = lane >> 4;                // k-group (co = g*8 + j)

    f32x4 acc = {0.0f, 0.0f, 0.0f, 0.0f};
    float sacc = 0.0f;

    // Wave wv handles batches b in [chunk*32 + wv*8, +8), one batch/round.
    // Lane loads x[b][ci][g*8+j][m] at float idx ((b*32+ci)*32+g*8+j)*16+m
    // -> 8 dwords, stride 64B. Batch stride: 32*32*16 = 16384 floats (64KB).
    const int b0 = chunk * 32 + wv * 8;
    const float* p = x + ((size_t)(b0 * 32 + ci) * 32 + g * 8) * 16 + m;

    float bufA[8], bufB[8];

    auto ld = [&](float (&d)[8], const float* q) {
#pragma unroll
        for (int j = 0; j < 8; ++j) d[j] = q[j * 16];
    };
    auto step = [&](float (&buf)[8]) {
        union { bf16x8 v; unsigned short h[8]; } fu;
#pragma unroll
        for (int j = 0; j < 8; ++j) {
            sacc += buf[j];                     // exact fp32 column sum
            fu.h[j] = f2bf(buf[j]);
        }
        acc = __builtin_amdgcn_mfma_f32_16x16x32_bf16(fu.v, fu.v, acc, 0, 0, 0);
    };

    // 8 rounds, depth-2 ping-pong prefetch (named buffers, rule #20).
    ld(bufA, p);
    ld(bufB, p + 16384);
    p += 2 * 16384;
#pragma unroll
    for (int rr = 0; rr < 4; ++rr) {
        step(bufA);
        if (rr < 3) { ld(bufA, p); p += 16384; }
        step(bufB);
        if (rr < 3) { ld(bufB, p); p += 16384; }
    }

    // S[m]: sum sacc across the 4 k-groups (lanes 16 apart).
    sacc += __shfl_xor(sacc, 16, 64);
    sacc += __shfl_xor(sacc, 32, 64);

    // C/D layout (m89-verified): lane holds P[row=g*4+q][col=m], q=0..3.
    __shared__ float red[4][272];
#pragma unroll
    for (int q = 0; q < 4; ++q)
        red[wv][(g * 4 + q) * 17 + m] = acc[q];
    if (g == 0) red[wv][m * 17 + 16] = sacc;
    __syncthreads();

    float* slot = ws + WS_PART + (ci * NCHUNK + chunk) * PART_STRIDE;
    for (int e = tid; e < 272; e += 256)
        slot[e] = red[0][e] + red[1][e] + red[2][e] + red[3][e];
}

// ---------------------------------------------------------------------------
// Kernel 2: reduce chunk partials, Newton-Schulz inverse sqrt, then FOLD the
// epilogue constants: WG = W*gamma (per column), C0 = beta - (mean@W)*gamma.
// 32 blocks (one per ci) of 256 threads.
// ---------------------------------------------------------------------------
__global__ __launch_bounds__(256) void k_ns(const float* __restrict__ gamma,
                                            const float* __restrict__ beta,
                                            float* __restrict__ ws) {
    const int ci  = blockIdx.x;
    const int tid = threadIdx.x;
    const int r = tid >> 4, c = tid & 15;

    __shared__ float red2[272];
    __shared__ float sig[16][17];
    __shared__ float pm[16][17];
    __shared__ float t1[16][17];
    __shared__ float t2[16][17];
    __shared__ float trace_s;

    const float* base = ws + WS_PART + (size_t)ci * NCHUNK * PART_STRIDE;
    for (int e = tid; e < 272; e += 256) {
        float s = 0.0f;
#pragma unroll
        for (int ch = 0; ch < NCHUNK; ++ch)
            s += base[ch * PART_STRIDE + e];
        red2[e] = s;
    }
    __syncthreads();

    // sigma[r][c] = (P_rc - S_r*S_c/N) / (N-1)   (canonical partial layout)
    const float P_rc = red2[r * 17 + c];
    const float S_r  = red2[r * 17 + 16];
    const float S_c  = red2[c * 17 + 16];
    sig[r][c] = (P_rc - S_r * S_c * INV_N) * INV_NM1;
    __syncthreads();

    if (tid == 0) {
        float tr = 0.0f;
        for (int i = 0; i < 16; ++i) tr += sig[i][i];
        trace_s = tr;
    }
    __syncthreads();
    const float tr = trace_s;

    sig[r][c] = sig[r][c] / tr;                 // sigma_n
    pm[r][c]  = (r == c) ? 1.0f : 0.0f;
    __syncthreads();

    for (int it = 0; it < 5; ++it) {
        float a = 0.0f;
        for (int k = 0; k < 16; ++k) a += pm[r][k] * pm[k][c];
        t1[r][c] = a;
        __syncthreads();
        float b2 = 0.0f;
        for (int k = 0; k < 16; ++k) b2 += t1[r][k] * pm[k][c];
        t2[r][c] = b2;
        __syncthreads();
        float d = 0.0f;
        for (int k = 0; k < 16; ++k) d += t2[r][k] * sig[k][c];
        const float np = 0.5f * (3.0f * pm[r][c] - d);
        __syncthreads();
        pm[r][c] = np;
        __syncthreads();
    }

    const float inv_sqrt_tr = 1.0f / sqrtf(tr); // W = pm * inv_sqrt_tr
    const float gc = gamma[ci * 16 + c];
    ws[WS_WG + ci * 256 + r * 16 + c] = pm[r][c] * inv_sqrt_tr * gc;
    if (r == 0) {
        float s = 0.0f;
        for (int a = 0; a < 16; ++a) {
            const float mean_a = red2[a * 17 + 16] * INV_N;
            s += mean_a * pm[a][c];
        }
        ws[WS_C0 + ci * 16 + c] = beta[ci * 16 + c] - gc * s * inv_sqrt_tr;
    }
}

// ---------------------------------------------------------------------------
// Kernel 3: out = x @ WG + C0 (all normalization constants pre-folded).
// Grid doubled to 2048 (8 blocks/CU) for latency hiding of nt-stores +
// L3 reads; 16 iterations per block, depth-1 prefetch as before.
// ---------------------------------------------------------------------------
__global__ __launch_bounds__(256) void k_apply(const float* __restrict__ x,
                                               const float* __restrict__ ws,
                                               float* __restrict__ out) {
    const int ci    = blockIdx.x & 31;
    const int chunk = blockIdx.x >> 5;          // 0..63
    const int tid   = threadIdx.x;
    const int sub   = tid & 3;
    const int quad  = tid >> 2;
    const int b0    = sub * 4;

    float wg[16][4];
    const float* WG = ws + WS_WG + ci * 256;
#pragma unroll
    for (int a = 0; a < 16; ++a) {
        const float4 w4 = *reinterpret_cast<const float4*>(WG + a * 16 + b0);
        wg[a][0] = w4.x; wg[a][1] = w4.y; wg[a][2] = w4.z; wg[a][3] = w4.w;
    }
    const float4 c4 = *reinterpret_cast<const float4*>(ws + WS_C0 + ci * 16 + b0);
    const float c0[4] = {c4.x, c4.y, c4.z, c4.w};

    // n = chunk*1024 + it*64 + quad; b = chunk*32 + it*2 + (quad>>5).
    const size_t base =
        (((size_t)(chunk * 32 + (quad >> 5)) * 32 + ci) * 32 + (quad & 31)) * 16;
    const float* p = x + base;
    float* q = out + base + b0;

    auto body = [&](const float4& f0, const float4& f1,
                    const float4& f2, const float4& f3, float* qq) {
        const float v[16] = {f0.x, f0.y, f0.z, f0.w,  f1.x, f1.y, f1.z, f1.w,
                             f2.x, f2.y, f2.z, f2.w,  f3.x, f3.y, f3.z, f3.w};
        float oacc[4] = {c0[0], c0[1], c0[2], c0[3]};
#pragma unroll
        for (int a = 0; a < 16; ++a) {
#pragma unroll
            for (int i = 0; i < 4; ++i) oacc[i] += v[a] * wg[a][i];
        }
        f32x4 o;
        o.x = oacc[0]; o.y = oacc[1]; o.z = oacc[2]; o.w = oacc[3];
        __builtin_nontemporal_store(o, reinterpret_cast<f32x4*>(qq));
    };

    float4 f0 = *reinterpret_cast<const float4*>(p);
    float4 f1 = *reinterpret_cast<const float4*>(p + 4);
    float4 f2 = *reinterpret_cast<const float4*>(p + 8);
    float4 f3 = *reinterpret_cast<const float4*>(p + 12);

    for (int it = 0; it < 15; ++it) {
        const float* pn = p + 32768;
        const float4 g0 = *reinterpret_cast<const float4*>(pn);
        const float4 g1 = *reinterpret_cast<const float4*>(pn + 4);
        const float4 g2 = *reinterpret_cast<const float4*>(pn + 8);
        const float4 g3 = *reinterpret_cast<const float4*>(pn + 12);

        body(f0, f1, f2, f3, q);

        f0 = g0; f1 = g1; f2 = g2; f3 = g3;
        p = pn; q += 32768;
    }
    body(f0, f1, f2, f3, q);                    // peeled last iteration
}

// ---------------------------------------------------------------------------
extern "C" void kernel_launch(void* const* d_in, const int* in_sizes, int n_in,
                              void* d_out, int out_size, void* d_ws, size_t ws_size,
                              hipStream_t stream) {
    const float* x     = (const float*)d_in[0];
    const float* gamma = (const float*)d_in[1];
    const float* beta  = (const float*)d_in[2];
    float* out = (float*)d_out;
    float* ws  = (float*)d_ws;

    k_stats<<<dim3(2048), dim3(256), 0, stream>>>(x, ws);
    k_ns<<<dim3(32), dim3(256), 0, stream>>>(gamma, beta, ws);
    k_apply<<<dim3(2048), dim3(256), 0, stream>>>(x, ws, out);
}

// Round 12
// 76.041 us; speedup vs baseline: 1.0126x; 1.0126x over previous
//
#include <hip/hip_runtime.h>
#include <hip/hip_bf16.h>
#include <math.h>

// Problem constants (reference: B=2048, CI=32, CO=32, A=16, ITER_NUM=5)
constexpr int CI = 32;
constexpr int CO = 32;
constexpr float INV_N   = 1.0f / 65536.0f;
constexpr float INV_NM1 = 1.0f / 65535.0f;

constexpr int NCHUNK = 32;                 // stats chunks per capsule
constexpr int PART_STRIDE = 272;           // 16 rows * 17 (16 cols + 1 sum)

// d_ws float layout (no zero-init required):
//   WS_PART: [CI][NCHUNK][272] per-block partials, canonical row*17+col
//   WS_WG:   [CI][16][16]  folded W*gamma
//   WS_C0:   [CI][16]      folded bias: beta - (mean @ W)*gamma
constexpr int WS_PART = 0;
constexpr int WS_WG   = CI * NCHUNK * PART_STRIDE;   // 278528
constexpr int WS_C0   = WS_WG + CI * 256;

constexpr int BSTRIDE = 16384;             // floats per batch (64 KB)

using f32x4  = __attribute__((ext_vector_type(4))) float;
using bf16x8 = __attribute__((ext_vector_type(8))) short;

// ---------------------------------------------------------------------------
// Kernel 1 (MFMA): per-capsule raw sums S[a] and Gram P[a][b] = sum x_a x_b.
// Grid: 32 ci * 32 chunks = 1024 blocks of 256 threads (4 blocks/CU — R11
// measured that MORE blocks regress; R10 16-round shape kept).
// One mfma_f32_16x16x32_bf16 consumes 32 vectors (one batch's 32 co-slots).
// Gram trick: A and B fragments are IDENTICAL per-lane (row/col = lane&15,
// k = (lane>>4)*8+reg), so one 8-dword load set feeds both operands.
// R12 LEVER: depth-4 named-buffer prefetch — each buffer reloads 3 steps
// (~400cy of issue) before its consume, 8KB/wave in flight, so the ~900cy+
// HBM latency hides (depth-2 re-issued only ~100cy ahead -> hard stall).
// ---------------------------------------------------------------------------
__global__ __launch_bounds__(256) void k_stats(const float* __restrict__ x,
                                               float* __restrict__ ws) {
    const int ci    = blockIdx.x & 31;
    const int chunk = blockIdx.x >> 5;          // 0..31
    const int tid   = threadIdx.x;
    const int lane  = tid & 63;
    const int wv    = tid >> 6;
    const int m     = lane & 15;                // row/col index this lane owns
    const int g     = lane >> 4;                // k-group (co = g*8 + j)

    f32x4 acc = {0.0f, 0.0f, 0.0f, 0.0f};
    float sacc = 0.0f;

    // Wave wv handles batches b in [chunk*64 + wv*16, +16), one batch/round.
    // Lane loads x[b][ci][g*8+j][m] at float idx ((b*32+ci)*32+g*8+j)*16+m
    // -> 8 dwords, stride 64B; wave covers one aligned 2KB block per round.
    const int b0 = chunk * 64 + wv * 16;
    const float* p = x + ((size_t)(b0 * 32 + ci) * 32 + g * 8) * 16 + m;

    float bA[8], bB[8], bC[8], bD[8];

    auto ld = [&](float (&d)[8], const float* q) {
#pragma unroll
        for (int j = 0; j < 8; ++j) d[j] = q[j * 16];
    };
    auto step = [&](float (&buf)[8]) {
        union { bf16x8 v; unsigned short h[8]; } fu;
#pragma unroll
        for (int j = 0; j < 8; ++j) {
            sacc += buf[j];                     // exact fp32 column sum
            // scalar cast -> compiler emits v_cvt_pk_bf16_f32 pairs (m240)
            fu.h[j] = __bfloat16_as_ushort(__float2bfloat16(buf[j]));
        }
        acc = __builtin_amdgcn_mfma_f32_16x16x32_bf16(fu.v, fu.v, acc, 0, 0, 0);
    };

    // 16 rounds, depth-4 rotation (named buffers only — rule #20).
    ld(bA, p);
    ld(bB, p + BSTRIDE);
    ld(bC, p + 2 * BSTRIDE);
    ld(bD, p + 3 * BSTRIDE);
    p += 4 * BSTRIDE;
#pragma unroll
    for (int rr = 0; rr < 4; ++rr) {
        step(bA); if (rr < 3) ld(bA, p);
        step(bB); if (rr < 3) ld(bB, p + BSTRIDE);
        step(bC); if (rr < 3) ld(bC, p + 2 * BSTRIDE);
        step(bD); if (rr < 3) { ld(bD, p + 3 * BSTRIDE); p += 4 * BSTRIDE; }
    }

    // S[m]: sum sacc across the 4 k-groups (lanes 16 apart).
    sacc += __shfl_xor(sacc, 16, 64);
    sacc += __shfl_xor(sacc, 32, 64);

    // C/D layout (m89-verified): lane holds P[row=g*4+q][col=m], q=0..3.
    __shared__ float red[4][272];
#pragma unroll
    for (int q = 0; q < 4; ++q)
        red[wv][(g * 4 + q) * 17 + m] = acc[q];
    if (g == 0) red[wv][m * 17 + 16] = sacc;
    __syncthreads();

    float* slot = ws + WS_PART + (ci * NCHUNK + chunk) * PART_STRIDE;
    for (int e = tid; e < 272; e += 256)
        slot[e] = red[0][e] + red[1][e] + red[2][e] + red[3][e];
}

// ---------------------------------------------------------------------------
// Kernel 2: reduce chunk partials, Newton-Schulz inverse sqrt, then FOLD the
// epilogue constants: WG = W*gamma (per column), C0 = beta - (mean@W)*gamma.
// 32 blocks (one per ci) of 256 threads.
// ---------------------------------------------------------------------------
__global__ __launch_bounds__(256) void k_ns(const float* __restrict__ gamma,
                                            const float* __restrict__ beta,
                                            float* __restrict__ ws) {
    const int ci  = blockIdx.x;
    const int tid = threadIdx.x;
    const int r = tid >> 4, c = tid & 15;

    __shared__ float red2[272];
    __shared__ float sig[16][17];
    __shared__ float pm[16][17];
    __shared__ float t1[16][17];
    __shared__ float t2[16][17];
    __shared__ float trace_s;

    const float* base = ws + WS_PART + (size_t)ci * NCHUNK * PART_STRIDE;
    for (int e = tid; e < 272; e += 256) {
        float s = 0.0f;
#pragma unroll
        for (int ch = 0; ch < NCHUNK; ++ch)
            s += base[ch * PART_STRIDE + e];
        red2[e] = s;
    }
    __syncthreads();

    // sigma[r][c] = (P_rc - S_r*S_c/N) / (N-1)   (canonical partial layout)
    const float P_rc = red2[r * 17 + c];
    const float S_r  = red2[r * 17 + 16];
    const float S_c  = red2[c * 17 + 16];
    sig[r][c] = (P_rc - S_r * S_c * INV_N) * INV_NM1;
    __syncthreads();

    if (tid == 0) {
        float tr = 0.0f;
        for (int i = 0; i < 16; ++i) tr += sig[i][i];
        trace_s = tr;
    }
    __syncthreads();
    const float tr = trace_s;

    sig[r][c] = sig[r][c] / tr;                 // sigma_n
    pm[r][c]  = (r == c) ? 1.0f : 0.0f;
    __syncthreads();

    for (int it = 0; it < 5; ++it) {
        float a = 0.0f;
        for (int k = 0; k < 16; ++k) a += pm[r][k] * pm[k][c];
        t1[r][c] = a;
        __syncthreads();
        float b2 = 0.0f;
        for (int k = 0; k < 16; ++k) b2 += t1[r][k] * pm[k][c];
        t2[r][c] = b2;
        __syncthreads();
        float d = 0.0f;
        for (int k = 0; k < 16; ++k) d += t2[r][k] * sig[k][c];
        const float np = 0.5f * (3.0f * pm[r][c] - d);
        __syncthreads();
        pm[r][c] = np;
        __syncthreads();
    }

    const float inv_sqrt_tr = 1.0f / sqrtf(tr); // W = pm * inv_sqrt_tr
    const float gc = gamma[ci * 16 + c];
    ws[WS_WG + ci * 256 + r * 16 + c] = pm[r][c] * inv_sqrt_tr * gc;
    if (r == 0) {
        float s = 0.0f;
        for (int a = 0; a < 16; ++a) {
            const float mean_a = red2[a * 17 + 16] * INV_N;
            s += mean_a * pm[a][c];
        }
        ws[WS_C0 + ci * 16 + c] = beta[ci * 16 + c] - gc * s * inv_sqrt_tr;
    }
}

// ---------------------------------------------------------------------------
// Kernel 3: out = x @ WG + C0 (all normalization constants pre-folded).
// EXACT R10 version (grid 1024; R11's grid doubling regressed).
// ---------------------------------------------------------------------------
__global__ __launch_bounds__(256) void k_apply(const float* __restrict__ x,
                                               const float* __restrict__ ws,
                                               float* __restrict__ out) {
    const int ci    = blockIdx.x & 31;
    const int chunk = blockIdx.x >> 5;          // 0..31
    const int tid   = threadIdx.x;
    const int sub   = tid & 3;
    const int quad  = tid >> 2;
    const int b0    = sub * 4;

    float wg[16][4];
    const float* WG = ws + WS_WG + ci * 256;
#pragma unroll
    for (int a = 0; a < 16; ++a) {
        const float4 w4 = *reinterpret_cast<const float4*>(WG + a * 16 + b0);
        wg[a][0] = w4.x; wg[a][1] = w4.y; wg[a][2] = w4.z; wg[a][3] = w4.w;
    }
    const float4 c4 = *reinterpret_cast<const float4*>(ws + WS_C0 + ci * 16 + b0);
    const float c0[4] = {c4.x, c4.y, c4.z, c4.w};

    const size_t base =
        (((size_t)(chunk * 64 + (quad >> 5)) * 32 + ci) * 32 + (quad & 31)) * 16;
    const float* p = x + base;
    float* q = out + base + b0;

    auto body = [&](const float4& f0, const float4& f1,
                    const float4& f2, const float4& f3, float* qq) {
        const float v[16] = {f0.x, f0.y, f0.z, f0.w,  f1.x, f1.y, f1.z, f1.w,
                             f2.x, f2.y, f2.z, f2.w,  f3.x, f3.y, f3.z, f3.w};
        float oacc[4] = {c0[0], c0[1], c0[2], c0[3]};
#pragma unroll
        for (int a = 0; a < 16; ++a) {
#pragma unroll
            for (int i = 0; i < 4; ++i) oacc[i] += v[a] * wg[a][i];
        }
        f32x4 o;
        o.x = oacc[0]; o.y = oacc[1]; o.z = oacc[2]; o.w = oacc[3];
        __builtin_nontemporal_store(o, reinterpret_cast<f32x4*>(qq));
    };

    float4 f0 = *reinterpret_cast<const float4*>(p);
    float4 f1 = *reinterpret_cast<const float4*>(p + 4);
    float4 f2 = *reinterpret_cast<const float4*>(p + 8);
    float4 f3 = *reinterpret_cast<const float4*>(p + 12);

    for (int it = 0; it < 31; ++it) {
        const float* pn = p + 32768;
        const float4 g0 = *reinterpret_cast<const float4*>(pn);
        const float4 g1 = *reinterpret_cast<const float4*>(pn + 4);
        const float4 g2 = *reinterpret_cast<const float4*>(pn + 8);
        const float4 g3 = *reinterpret_cast<const float4*>(pn + 12);

        body(f0, f1, f2, f3, q);

        f0 = g0; f1 = g1; f2 = g2; f3 = g3;
        p = pn; q += 32768;
    }
    body(f0, f1, f2, f3, q);                    // peeled last iteration
}

// ---------------------------------------------------------------------------
extern "C" void kernel_launch(void* const* d_in, const int* in_sizes, int n_in,
                              void* d_out, int out_size, void* d_ws, size_t ws_size,
                              hipStream_t stream) {
    const float* x     = (const float*)d_in[0];
    const float* gamma = (const float*)d_in[1];
    const float* beta  = (const float*)d_in[2];
    float* out = (float*)d_out;
    float* ws  = (float*)d_ws;

    k_stats<<<dim3(1024), dim3(256), 0, stream>>>(x, ws);
    k_ns<<<dim3(32), dim3(256), 0, stream>>>(gamma, beta, ws);
    k_apply<<<dim3(1024), dim3(256), 0, stream>>>(x, ws, out);
}